// Round 14
// baseline (486.615 us; speedup 1.0000x reference)
//
#include <hip/hip_runtime.h>

constexpr int T = 168;
constexpr int P = 16;
constexpr int H = 24;

typedef float v2f __attribute__((ext_vector_type(2)));

__device__ __forceinline__ v2f mk2(float a, float b) { v2f r; r[0] = a; r[1] = b; return r; }
__device__ __forceinline__ v2f bc2(float a)          { v2f r; r[0] = a; r[1] = a; return r; }
// 2 fp32 FMAs in one instruction (v_pk_fma_f32).
__device__ __forceinline__ v2f pkfma(v2f a, v2f b, v2f c) {
    return __builtin_elementwise_fma(a, b, c);
}

__device__ __forceinline__ float rcp_f(float x) { return __builtin_amdgcn_rcpf(x); }
__device__ __forceinline__ float sigm_f(float x) { return rcp_f(1.f + __expf(-x)); }
// tanh(x) = 2*sigmoid(2x) - 1
__device__ __forceinline__ float tanh_fast(float x) {
    return fmaf(2.f, rcp_f(1.f + __expf(-2.f * x)), -1.f);
}

// Broadcast lane k's value of v to all lanes via v_readlane (VALU/SALU path,
// ZERO LDS traffic — the whole point of R18). k is a literal from unrolling.
__device__ __forceinline__ float rdlane(float v, int k) {
    return __builtin_bit_cast(float,
        __builtin_amdgcn_readlane(__builtin_bit_cast(int, v), k));
}

#define KEEP2(v) asm volatile("" : "+v"(v))
// Intra-wave LDS write->read ordering + compiler reorder fence.
#define LDS_SYNC() asm volatile("s_waitcnt lgkmcnt(0)" ::: "memory")

// 4 packed FMAs: acc += v4.{x,y,z,w} * w[b..b+3]
#define PK4(acc_, v4_, w_, b_) do {                       \
    acc_ = pkfma(bc2((v4_).x), (w_)[(b_)],     acc_);     \
    acc_ = pkfma(bc2((v4_).y), (w_)[(b_) + 1], acc_);     \
    acc_ = pkfma(bc2((v4_).z), (w_)[(b_) + 2], acc_);     \
    acc_ = pkfma(bc2((v4_).w), (w_)[(b_) + 3], acc_); } while (0)

// Gate nonlinearity + state update; returns new h (valid on lanes 0..23).
__device__ __forceinline__ float act_update(v2f g, int lane, int half, float& c)
{
    float a0 = sigm_f(g[0]);                        // i (half0) | f (half1)
    float px = (half == 0) ? g[1] + g[1] : g[1];
    float sv = sigm_f(px);
    float a1 = (half == 0) ? sv + sv - 1.f : sv;    // tanh(g) | o
    float fa = __shfl(a0, lane + 24);
    float oa = __shfl(a1, lane + 24);
    c = fmaf(fa, c, a0 * a1);
    return oa * tanh_fast(c);
}

// One L1 timestep: x from the LDS chunk buffer (broadcast b128), h via
// readlane from the register-resident state; writes tanh(h) for the handoff.
#define L1S(xlsrow_, hreg_, c_, tdst_) do {                            \
    v2f g_ = bias;                                                     \
    _Pragma("unroll")                                                  \
    for (int j_ = 0; j_ < P / 4; ++j_) {                               \
        float4 v_ = ((const float4*)(xlsrow_))[j_];                    \
        PK4(g_, v_, w, 4 * j_);                                        \
    }                                                                  \
    _Pragma("unroll")                                                  \
    for (int k_ = 0; k_ < H; ++k_)                                     \
        g_ = pkfma(bc2(rdlane(hreg_, k_)), w[H + k_], g_);             \
    hreg_ = act_update(g_, lane, half, c_);                            \
    float th_ = tanh_fast(hreg_);                                      \
    if (lane < H) (tdst_)[lane] = th_;                                 \
} while (0)

// One L2 timestep: t1 via ONE per-lane ds_read_b32 + readlane broadcasts;
// h2 via readlane from register state. No b128 LDS reads at all.
#define L2S(tsrc_, hreg_, c_) do {                                     \
    float tv_ = (tsrc_)[lane & 31];                                    \
    v2f f_ = bias;                                                     \
    _Pragma("unroll")                                                  \
    for (int k_ = 0; k_ < H; ++k_)                                     \
        f_ = pkfma(bc2(rdlane(tv_, k_)), w[k_], f_);                   \
    _Pragma("unroll")                                                  \
    for (int k_ = 0; k_ < H; ++k_)                                     \
        f_ = pkfma(bc2(rdlane(hreg_, k_)), w[H + k_], f_);             \
    hreg_ = act_update(f_, lane, half, c_);                            \
} while (0)

// R18: de-bottleneck the LDS pipe via readlane broadcasts.
// Evidence chain: R15 steady 335us = 9600cy/superstep; per-CU LDS demand =
// 8 blocks x (24+48 broadcast ds_read_b128 x ~12cy + bperm/writes) ~= 8400cy
// => LDS ~88% busy = THE bottleneck. Confirms: barrier halving neutral (R15),
// occupancy drop slower (R16), adding x LDS reads slightly worse (R17),
// x-latency prefetch neutral (R17). VALU (~5-6k cy/SIMD, pk_fma@4cy + trans)
// is secondary at 62%.
// Change: recurrent state h1/h2 stays in REGISTERS (lane u holds h[u]); the
// Whh/Wih2 matvec broadcasts use v_readlane (constant lane, SGPR operand
// into v_pk_fma_f32) instead of LDS b128 reads. t1 handoff = 1 ds_write_b32
// + 1 ds_read_b32 per row-step + readlanes. h1s/h2s LDS arrays deleted from
// the loop. Block LDS/superstep: ~72 b128 -> ~8 b32 + x staging => LDS <25%.
// Keeps: R15 superstep structure (84 barriers), wave0=L1/wave1=L2, t1 double
// buffer, R17 x chunk staging (FETCH halved to 22MB), uniform weight init,
// amdgpu_num_vgpr(128), 2048 blocks x 2 waves = 4 waves/SIMD.
__global__ __attribute__((amdgpu_flat_work_group_size(128, 128),
                          amdgpu_num_vgpr(128)))
void lstm2_split7(const float* __restrict__ x,
                  const float* __restrict__ Wih1, const float* __restrict__ Whh1,
                  const float* __restrict__ bih1, const float* __restrict__ bhh1,
                  const float* __restrict__ Wih2, const float* __restrict__ Whh2,
                  const float* __restrict__ bih2, const float* __restrict__ bhh2,
                  const float* __restrict__ W1, const float* __restrict__ b1,
                  const float* __restrict__ W2, const float* __restrict__ b2,
                  float* __restrict__ out)
{
    const int tid  = threadIdx.x;
    const int wid  = tid >> 6;                    // 0: L1 wave, 1: L2 wave
    const int lane = tid & 63;
    const int s    = (lane < 48) ? lane : 47;     // clamp idle lanes
    const int u    = s % H;                       // unit 0..23
    const int half = s / H;                       // 0: {i,g}, 1: {f,o}
    const int q0   = half * H + u;                // i or f gate row
    const int q1   = (2 + half) * H + u;          // g or o gate row
    const int rowA = blockIdx.x * 2;
    const int rowB = rowA + 1;

    // ---- uniform weight init: 48 v2f = 96 regs, same mapping both waves ----
    // w[0..23]:  input-weight pairs {q0,q1} (cols >= nin zero-padded)
    // w[24..47]: recurrent pairs {q0,q1}
    const float* __restrict__ Wi = wid ? Wih2 : Wih1;
    const float* __restrict__ Wh = wid ? Whh2 : Whh1;
    const float* __restrict__ bi = wid ? bih2 : bih1;
    const float* __restrict__ bh = wid ? bhh2 : bhh1;
    const int nin = wid ? H : P;                  // 24 | 16 (wave-uniform)

    v2f w[48];
    #pragma unroll
    for (int k = 0; k < H; ++k)
        w[k] = (k < nin) ? mk2(Wi[q0 * nin + k], Wi[q1 * nin + k]) : bc2(0.f);
    #pragma unroll
    for (int k = 0; k < H; ++k)
        w[H + k] = mk2(Wh[q0 * H + k], Wh[q1 * H + k]);
    v2f bias = mk2(bi[q0] + bh[q0], bi[q1] + bh[q1]);

    #pragma unroll
    for (int k = 0; k < 48; ++k) KEEP2(w[k]);
    KEEP2(bias);

    __shared__ __align__(16) float t1s[2][2][2][32];    // [buf][step][row]
    __shared__ __align__(16) float xls[2][2][8][16];    // [buf][row][step][col]

    const float* __restrict__ xA = x + (size_t)rowA * T * P;  // wave-uniform
    const float* __restrict__ xB = x + (size_t)rowB * T * P;

    float cA = 0.f, cB = 0.f;     // c1 (wave0) / c2 (wave1)
    float hA = 0.f, hB = 0.f;     // register-resident recurrent state

    // x-stage lane mapping (wave0): lanes 0-31 row A, lanes 32-63 row B;
    // each lane owns one float4 of the 512B per-row chunk (8 steps).
    const int xr  = lane >> 5;
    const int xo4 = lane & 31;
    const float* __restrict__ xbase = xr ? xB : xA;
    float4 xst;                                    // in-flight chunk staging

    // ---- superstep 0: wave0 = L1 steps {0,1} (h starts 0 in registers) ----
    if (wid == 0) {
        xst = ((const float4*)xbase)[xo4];         // chunk 0
        ((float4*)xls[0][xr])[xo4] = xst;          // vmcnt waited via use
        xst = ((const float4*)(xbase + 128))[xo4]; // chunk 1 in flight
        LDS_SYNC();                                // chunk 0 visible (own wave)
        L1S(xls[0][0][0], hA, cA, t1s[0][0][0]);
        L1S(xls[0][1][0], hB, cB, t1s[0][0][1]);
        L1S(xls[0][0][1], hA, cA, t1s[0][1][0]);
        L1S(xls[0][1][1], hB, cB, t1s[0][1][1]);
    }
    LDS_SYNC();
    __builtin_amdgcn_s_barrier();

    // ---- supersteps 1..83: wave0 = L1 {2s,2s+1}; wave1 = L2 {2s-2,2s-1} ----
    for (int ss = 1; ss < T / 2; ++ss) {
        if (wid == 0) {
            if ((ss & 3) == 0) {                   // rotate 8-step x chunk
                const int ci = ss >> 2;            // 1..20
                ((float4*)xls[ci & 1][xr])[xo4] = xst;
                if (ci < 20)
                    xst = ((const float4*)(xbase + (ci + 1) * 128))[xo4];
                LDS_SYNC();                        // chunk ci visible
            }
            const int xb = (ss >> 2) & 1;
            const int ta = 2 * ss;
            L1S(xls[xb][0][ta & 7],       hA, cA, t1s[ss & 1][0][0]);
            L1S(xls[xb][1][ta & 7],       hB, cB, t1s[ss & 1][0][1]);
            L1S(xls[xb][0][(ta + 1) & 7], hA, cA, t1s[ss & 1][1][0]);
            L1S(xls[xb][1][(ta + 1) & 7], hB, cB, t1s[ss & 1][1][1]);
        } else {
            const int pb = (ss - 1) & 1;
            L2S(t1s[pb][0][0], hA, cA);
            L2S(t1s[pb][0][1], hB, cB);
            L2S(t1s[pb][1][0], hA, cA);
            L2S(t1s[pb][1][1], hB, cB);
        }
        LDS_SYNC();
        __builtin_amdgcn_s_barrier();
    }

    // ---- tail (wave1 only): L2 steps {166,167} from buf 1, then head ----
    if (wid == 1) {
        L2S(t1s[1][0][0], hA, cA);
        L2S(t1s[1][0][1], hB, cB);
        L2S(t1s[1][1][0], hA, cA);
        L2S(t1s[1][1][1], hB, cB);

        // head: tanh -> fc1(16, relu) -> fc2(24); reuse stale t1s[0] as
        // scratch (wave0 has exited; wave1-private from here).
        if (lane < H) {
            t1s[0][0][0][lane] = tanh_fast(hA);
            t1s[0][0][1][lane] = tanh_fast(hB);
        }
        LDS_SYNC();
        if (lane < 16) {
            float accA = b1[lane], accB = b1[lane];
            #pragma unroll
            for (int j = 0; j < H; ++j) {
                float wv = W1[lane * H + j];
                accA = fmaf(t1s[0][0][0][j], wv, accA);
                accB = fmaf(t1s[0][0][1][j], wv, accB);
            }
            t1s[0][1][0][lane] = fmaxf(accA, 0.f);
            t1s[0][1][1][lane] = fmaxf(accB, 0.f);
        }
        LDS_SYNC();
        if (lane < H) {
            float accA = b2[lane], accB = b2[lane];
            #pragma unroll
            for (int j = 0; j < 16; ++j) {
                float wv = W2[lane * 16 + j];
                accA = fmaf(t1s[0][1][0][j], wv, accA);
                accB = fmaf(t1s[0][1][1][j], wv, accB);
            }
            out[(size_t)rowA * H + lane] = accA;
            out[(size_t)rowB * H + lane] = accB;
        }
    }
}

extern "C" void kernel_launch(void* const* d_in, const int* in_sizes, int n_in,
                              void* d_out, int out_size, void* d_ws, size_t ws_size,
                              hipStream_t stream)
{
    const float* x    = (const float*)d_in[0];
    const float* Wih1 = (const float*)d_in[1];
    const float* Whh1 = (const float*)d_in[2];
    const float* bih1 = (const float*)d_in[3];
    const float* bhh1 = (const float*)d_in[4];
    const float* Wih2 = (const float*)d_in[5];
    const float* Whh2 = (const float*)d_in[6];
    const float* bih2 = (const float*)d_in[7];
    const float* bhh2 = (const float*)d_in[8];
    const float* W1   = (const float*)d_in[9];
    const float* b1   = (const float*)d_in[10];
    const float* W2   = (const float*)d_in[11];
    const float* b2   = (const float*)d_in[12];
    float* out = (float*)d_out;

    const int B = in_sizes[0] / (T * P);             // 4096
    hipLaunchKernelGGL(lstm2_split7, dim3(B / 2), dim3(128), 0, stream,
                       x, Wih1, Whh1, bih1, bhh1, Wih2, Whh2, bih2, bhh2,
                       W1, b1, W2, b2, out);
}

// Round 15
// 410.714 us; speedup vs baseline: 1.1848x; 1.1848x over previous
//
#include <hip/hip_runtime.h>

constexpr int T = 168;
constexpr int P = 16;
constexpr int H = 24;

typedef float v2f __attribute__((ext_vector_type(2)));

__device__ __forceinline__ v2f mk2(float a, float b) { v2f r; r[0] = a; r[1] = b; return r; }
__device__ __forceinline__ v2f bc2(float a)          { v2f r; r[0] = a; r[1] = a; return r; }
// 2 fp32 FMAs in one instruction (v_pk_fma_f32).
__device__ __forceinline__ v2f pkfma(v2f a, v2f b, v2f c) {
    return __builtin_elementwise_fma(a, b, c);
}

__device__ __forceinline__ float rcp_f(float x) { return __builtin_amdgcn_rcpf(x); }
__device__ __forceinline__ float sigm_f(float x) { return rcp_f(1.f + __expf(-x)); }
// tanh(x) = 2*sigmoid(2x) - 1
__device__ __forceinline__ float tanh_fast(float x) {
    return fmaf(2.f, rcp_f(1.f + __expf(-2.f * x)), -1.f);
}

// Broadcast lane k's value of v via v_readlane (VALU, zero LDS traffic).
__device__ __forceinline__ float rdlane(float v, int k) {
    return __builtin_bit_cast(float,
        __builtin_amdgcn_readlane(__builtin_bit_cast(int, v), k));
}

#define KEEP2(v) asm volatile("" : "+v"(v))
// Intra-wave LDS write->read ordering + compiler reorder fence.
#define LDS_SYNC() asm volatile("s_waitcnt lgkmcnt(0)" ::: "memory")

// 4 packed FMAs: acc += v4.{x,y,z,w} * w[b..b+3]
#define PK4(acc_, v4_, w_, b_) do {                       \
    acc_ = pkfma(bc2((v4_).x), (w_)[(b_)],     acc_);     \
    acc_ = pkfma(bc2((v4_).y), (w_)[(b_) + 1], acc_);     \
    acc_ = pkfma(bc2((v4_).z), (w_)[(b_) + 2], acc_);     \
    acc_ = pkfma(bc2((v4_).w), (w_)[(b_) + 3], acc_); } while (0)

// Gate nonlinearity + state update; returns new h (valid on lanes 0..23).
__device__ __forceinline__ float act_update(v2f g, int lane, int half, float& c)
{
    float a0 = sigm_f(g[0]);                        // i (half0) | f (half1)
    float px = (half == 0) ? g[1] + g[1] : g[1];
    float sv = sigm_f(px);
    float a1 = (half == 0) ? sv + sv - 1.f : sv;    // tanh(g) | o
    float fa = __shfl(a0, lane + 24);
    float oa = __shfl(a1, lane + 24);
    c = fmaf(fa, c, a0 * a1);
    return oa * tanh_fast(c);
}

// One L1 timestep: x via DIRECT global float4 loads (R15-proven; R17 showed
// LDS staging of x is pure cost), h via readlane from register state
// (-6 ds_read_b128, +18 VALU: good trade on the LDS-bound pipe).
// Writes tanh(h) to LDS for the cross-wave handoff.
#define L1S(xrow_, hreg_, c_, tdst_) do {                              \
    v2f g_ = bias;                                                     \
    const float4* x4_ = (const float4*)(xrow_);                        \
    _Pragma("unroll")                                                  \
    for (int j_ = 0; j_ < P / 4; ++j_) {                               \
        float4 v_ = x4_[j_];                                           \
        PK4(g_, v_, w, 4 * j_);                                        \
    }                                                                  \
    _Pragma("unroll")                                                  \
    for (int k_ = 0; k_ < H; ++k_)                                     \
        g_ = pkfma(bc2(rdlane(hreg_, k_)), w[H + k_], g_);             \
    hreg_ = act_update(g_, lane, half, c_);                            \
    float th_ = tanh_fast(hreg_);                                      \
    if (lane < H) (tdst_)[lane] = th_;                                 \
} while (0)

// One L2 timestep: t-part stays b128 broadcast from LDS (cross-wave handoff,
// cheapest form — R18's mistake was converting this to readlane too);
// h-part via readlane from register state.
#define L2S(trow_, hreg_, c_) do {                                     \
    v2f f_ = bias;                                                     \
    _Pragma("unroll")                                                  \
    for (int k_ = 0; k_ < H / 4; ++k_) {                               \
        float4 tv_ = ((const float4*)(trow_))[k_];                     \
        PK4(f_, tv_, w, 4 * k_);                                       \
    }                                                                  \
    _Pragma("unroll")                                                  \
    for (int k_ = 0; k_ < H; ++k_)                                     \
        f_ = pkfma(bc2(rdlane(hreg_, k_)), w[H + k_], f_);             \
    hreg_ = act_update(f_, lane, half, c_);                            \
} while (0)

// R19: selective LDS-offload based on the R15/R17/R18 triangulation.
// Evidence: R15 (335us steady): LDS demand = 72 b128/block-superstep x 8
// blocks x ~12cy + bperm ~= 80% of the 9571cy period -> LDS-bound, VALU 62%
// second. R17 (+x LDS traffic): 363 (+8%) - consistent. R18 (ALL matvecs ->
// readlane, +60% VALU ops on matvecs): 437, VALU-work +30% = VALU-bound.
// The per-matvec trade (h-part -> readlane): +18 VALU (~+36cy issue) vs
// -6 b128 (~-72cy LDS) — favorable ONLY for h-parts (own-wave state).
// Change vs R15: h1/h2 register-resident (lane u holds h[u], R18-verified
// numerics), h-part matvecs via readlane; t-part KEEPS b128 broadcast
// (cross-wave, cheapest); x KEEPS direct global loads. LDS b128 per
// block-superstep: 72 -> 24 (-67%). Expect VALU to become the cap.
// Also explains occ 36%: ~64 arch + ~96 AGPR-parked weights ~= 160/wave ->
// 3 waves/SIMD; unchanged here.
// Keeps: R15 superstep structure (2 steps/superstep, 84 barriers), wave0=L1/
// wave1=L2, t1 double-buffer, uniform init, amdgpu_num_vgpr(128),
// 2048 blocks x 2 waves.
__global__ __attribute__((amdgpu_flat_work_group_size(128, 128),
                          amdgpu_num_vgpr(128)))
void lstm2_split8(const float* __restrict__ x,
                  const float* __restrict__ Wih1, const float* __restrict__ Whh1,
                  const float* __restrict__ bih1, const float* __restrict__ bhh1,
                  const float* __restrict__ Wih2, const float* __restrict__ Whh2,
                  const float* __restrict__ bih2, const float* __restrict__ bhh2,
                  const float* __restrict__ W1, const float* __restrict__ b1,
                  const float* __restrict__ W2, const float* __restrict__ b2,
                  float* __restrict__ out)
{
    const int tid  = threadIdx.x;
    const int wid  = tid >> 6;                    // 0: L1 wave, 1: L2 wave
    const int lane = tid & 63;
    const int s    = (lane < 48) ? lane : 47;     // clamp idle lanes
    const int u    = s % H;                       // unit 0..23
    const int half = s / H;                       // 0: {i,g}, 1: {f,o}
    const int q0   = half * H + u;                // i or f gate row
    const int q1   = (2 + half) * H + u;          // g or o gate row
    const int rowA = blockIdx.x * 2;
    const int rowB = rowA + 1;

    // ---- uniform weight init: 48 v2f = 96 regs, same mapping both waves ----
    // w[0..23]:  input-weight pairs {q0,q1} (cols >= nin zero-padded)
    // w[24..47]: recurrent pairs {q0,q1}
    const float* __restrict__ Wi = wid ? Wih2 : Wih1;
    const float* __restrict__ Wh = wid ? Whh2 : Whh1;
    const float* __restrict__ bi = wid ? bih2 : bih1;
    const float* __restrict__ bh = wid ? bhh2 : bhh1;
    const int nin = wid ? H : P;                  // 24 | 16 (wave-uniform)

    v2f w[48];
    #pragma unroll
    for (int k = 0; k < H; ++k)
        w[k] = (k < nin) ? mk2(Wi[q0 * nin + k], Wi[q1 * nin + k]) : bc2(0.f);
    #pragma unroll
    for (int k = 0; k < H; ++k)
        w[H + k] = mk2(Wh[q0 * H + k], Wh[q1 * H + k]);
    v2f bias = mk2(bi[q0] + bh[q0], bi[q1] + bh[q1]);

    #pragma unroll
    for (int k = 0; k < 48; ++k) KEEP2(w[k]);
    KEEP2(bias);

    __shared__ __align__(16) float t1s[2][2][2][32];    // [buf][step][row]

    const float* __restrict__ xA = x + (size_t)rowA * T * P;  // wave-uniform
    const float* __restrict__ xB = x + (size_t)rowB * T * P;

    float cA = 0.f, cB = 0.f;     // c1 (wave0) / c2 (wave1)
    float hA = 0.f, hB = 0.f;     // register-resident recurrent state

    // ---- superstep 0: wave0 = L1 steps {0,1} (h starts 0 in registers) ----
    if (wid == 0) {
        L1S(xA,     hA, cA, t1s[0][0][0]);
        L1S(xB,     hB, cB, t1s[0][0][1]);
        L1S(xA + P, hA, cA, t1s[0][1][0]);
        L1S(xB + P, hB, cB, t1s[0][1][1]);
    }
    LDS_SYNC();
    __builtin_amdgcn_s_barrier();

    // ---- supersteps 1..83: wave0 = L1 {2s,2s+1}; wave1 = L2 {2s-2,2s-1} ----
    for (int ss = 1; ss < T / 2; ++ss) {
        if (wid == 0) {
            const int ta = 2 * ss;
            L1S(xA + ta * P,       hA, cA, t1s[ss & 1][0][0]);
            L1S(xB + ta * P,       hB, cB, t1s[ss & 1][0][1]);
            L1S(xA + (ta + 1) * P, hA, cA, t1s[ss & 1][1][0]);
            L1S(xB + (ta + 1) * P, hB, cB, t1s[ss & 1][1][1]);
        } else {
            const int pb = (ss - 1) & 1;
            L2S(t1s[pb][0][0], hA, cA);
            L2S(t1s[pb][0][1], hB, cB);
            L2S(t1s[pb][1][0], hA, cA);
            L2S(t1s[pb][1][1], hB, cB);
        }
        LDS_SYNC();
        __builtin_amdgcn_s_barrier();
    }

    // ---- tail (wave1 only): L2 steps {166,167} from buf 1, then head ----
    if (wid == 1) {
        L2S(t1s[1][0][0], hA, cA);
        L2S(t1s[1][0][1], hB, cB);
        L2S(t1s[1][1][0], hA, cA);
        L2S(t1s[1][1][1], hB, cB);

        // head: tanh -> fc1(16, relu) -> fc2(24); reuse t1s as scratch
        // (wave0 has exited; wave1-private from here).
        if (lane < H) {
            t1s[0][0][0][lane] = tanh_fast(hA);
            t1s[0][0][1][lane] = tanh_fast(hB);
        }
        LDS_SYNC();
        if (lane < 16) {
            float accA = b1[lane], accB = b1[lane];
            #pragma unroll
            for (int j = 0; j < H; ++j) {
                float wv = W1[lane * H + j];
                accA = fmaf(t1s[0][0][0][j], wv, accA);
                accB = fmaf(t1s[0][0][1][j], wv, accB);
            }
            t1s[0][1][0][lane] = fmaxf(accA, 0.f);
            t1s[0][1][1][lane] = fmaxf(accB, 0.f);
        }
        LDS_SYNC();
        if (lane < H) {
            float accA = b2[lane], accB = b2[lane];
            #pragma unroll
            for (int j = 0; j < 16; ++j) {
                float wv = W2[lane * 16 + j];
                accA = fmaf(t1s[0][1][0][j], wv, accA);
                accB = fmaf(t1s[0][1][1][j], wv, accB);
            }
            out[(size_t)rowA * H + lane] = accA;
            out[(size_t)rowB * H + lane] = accB;
        }
    }
}

extern "C" void kernel_launch(void* const* d_in, const int* in_sizes, int n_in,
                              void* d_out, int out_size, void* d_ws, size_t ws_size,
                              hipStream_t stream)
{
    const float* x    = (const float*)d_in[0];
    const float* Wih1 = (const float*)d_in[1];
    const float* Whh1 = (const float*)d_in[2];
    const float* bih1 = (const float*)d_in[3];
    const float* bhh1 = (const float*)d_in[4];
    const float* Wih2 = (const float*)d_in[5];
    const float* Whh2 = (const float*)d_in[6];
    const float* bih2 = (const float*)d_in[7];
    const float* bhh2 = (const float*)d_in[8];
    const float* W1   = (const float*)d_in[9];
    const float* b1   = (const float*)d_in[10];
    const float* W2   = (const float*)d_in[11];
    const float* b2   = (const float*)d_in[12];
    float* out = (float*)d_out;

    const int B = in_sizes[0] / (T * P);             // 4096
    hipLaunchKernelGGL(lstm2_split8, dim3(B / 2), dim3(128), 0, stream,
                       x, Wih1, Whh1, bih1, bhh1, Wih2, Whh2, bih2, bhh2,
                       W1, b1, W2, b2, out);
}